// Round 17
// baseline (1634.389 us; speedup 1.0000x reference)
//
#include <hip/hip_runtime.h>
#include <hip/hip_bf16.h>

typedef __attribute__((ext_vector_type(8))) short bfrag;
typedef __attribute__((ext_vector_type(4))) float f32x4;

// fast shifted softplus: __logf/__expf intrinsics (rel err ~2^-21, threshold 2.3e-2)
__device__ __forceinline__ float ssp_f(float x) {
    return fmaxf(x, 0.f) + __logf(1.f + __expf(-fabsf(x))) - 0.6931471805599453f;
}

__device__ __forceinline__ unsigned short f2b(float x) {
    __hip_bfloat16 h = __float2bfloat16(x);
    return *(unsigned short*)&h;
}

__device__ __forceinline__ float b2f(unsigned short u) {
    unsigned int w = ((unsigned int)u) << 16;
    return *(float*)&w;
}

// ---------------- float dtype sniffer ----------------------------------------
__global__ void sniff_kernel(const unsigned int* __restrict__ raw, int* __restrict__ flag)
{
    __shared__ int cnt[256];
    const int t = threadIdx.x;
    unsigned int w = raw[t];
    unsigned int e = (w >> 7) & 0xFFu;
    cnt[t] = (e >= 100u && e <= 135u) ? 1 : 0;
    __syncthreads();
    for (int s = 128; s > 0; s >>= 1) {
        if (t < s) cnt[t] += cnt[t + s];
        __syncthreads();
    }
    if (t == 0) *flag = (cnt[0] >= 160) ? 1 : 0;   // 1 = floats are bf16
}

// ---------------- int width sniffer -------------------------------------------
__global__ void sniff_int_kernel(const unsigned int* __restrict__ z, int* __restrict__ iflag)
{
    __shared__ int cnt[128];
    const int t = threadIdx.x;
    cnt[t] = (z[2 * t + 1] == 0u) ? 1 : 0;
    __syncthreads();
    for (int s = 64; s > 0; s >>= 1) {
        if (t < s) cnt[t] += cnt[t + s];
        __syncthreads();
    }
    if (t == 0) *iflag = (cnt[0] >= 126) ? 1 : 0;  // 1 = ints are int64
}

// ---------------- converts -----------------------------------------------------
__global__ __launch_bounds__(256) void convert_kernel(
    const void* __restrict__ src, float* __restrict__ dst, int n,
    const int* __restrict__ flag)
{
    int i = blockIdx.x * 256 + threadIdx.x;
    if (i >= n) return;
    if (*flag) dst[i] = __bfloat162float(((const __hip_bfloat16*)src)[i]);
    else       dst[i] = ((const float*)src)[i];
}

__global__ __launch_bounds__(256) void convert_int_kernel(
    const void* __restrict__ src, int* __restrict__ dst, int n,
    const int* __restrict__ iflag)
{
    int i = blockIdx.x * 256 + threadIdx.x;
    if (i >= n) return;
    if (*iflag) dst[i] = (int)(((const long long*)src)[i]);
    else        dst[i] = ((const int*)src)[i];
}

// ---------------- node embedding gather ---------------------------------------
__global__ __launch_bounds__(256) void embed_kernel(
    const int* __restrict__ z, const float* __restrict__ embf,
    float* __restrict__ h, int NH)
{
    int idx = blockIdx.x * 256 + threadIdx.x;
    if (idx >= NH) return;
    h[idx] = embf[z[idx >> 7] * 128 + (idx & 127)];
}

// ---------------- CSR build ----------------------------------------------------
__global__ __launch_bounds__(256) void zero_int_kernel(int* p, int n)
{
    int i = blockIdx.x * 256 + threadIdx.x;
    if (i < n) p[i] = 0;
}

__global__ __launch_bounds__(256) void hist_kernel(const int* __restrict__ col,
                                                   int* __restrict__ count, int E)
{
    int e = blockIdx.x * 256 + threadIdx.x;
    if (e < E) atomicAdd(&count[col[e]], 1);
}

__global__ __launch_bounds__(256) void scan_kernel(const int* __restrict__ count,
                                                   int* __restrict__ rowptr,
                                                   int* __restrict__ next, int N)
{
    __shared__ int part[256];
    const int t = threadIdx.x;
    const int chunk = (N + 255) / 256;
    const int lo = t * chunk, hi = min(lo + chunk, N);
    int s = 0;
    for (int i = lo; i < hi; ++i) s += count[i];
    part[t] = s;
    __syncthreads();
    if (t == 0) {
        int run = 0;
        for (int i = 0; i < 256; ++i) { int v = part[i]; part[i] = run; run += v; }
        rowptr[N] = run;
    }
    __syncthreads();
    int run = part[t];
    for (int i = lo; i < hi; ++i) {
        rowptr[i] = run; next[i] = run;
        run += count[i];
    }
}

__global__ __launch_bounds__(256) void slot_kernel(const int* __restrict__ col,
                                                   int* __restrict__ next,
                                                   int* __restrict__ slot, int E)
{
    int e = blockIdx.x * 256 + threadIdx.x;
    if (e < E) slot[e] = atomicAdd(&next[col[e]], 1);
}

__global__ __launch_bounds__(256) void perm_kernel(const int* __restrict__ slot,
                                                   int* __restrict__ perm, int E)
{
    int e = blockIdx.x * 256 + threadIdx.x;
    if (e < E) perm[slot[e]] = e;
}

// ---------------- pre-permute edge data into sorted order ---------------------
__global__ __launch_bounds__(256) void prep_edges_kernel(
    const float* __restrict__ posf, const int* __restrict__ row,
    const int* __restrict__ col, const float* __restrict__ eattrf,
    const int* __restrict__ perm,
    int* __restrict__ rowS, int* __restrict__ colS,
    float* __restrict__ CS, float* __restrict__ ewS,
    unsigned short* __restrict__ eaS, int E, int NB)
{
    int p = blockIdx.x * 256 + threadIdx.x;
    if (p >= E) return;
    const int e = perm[p];
    const int r = row[e], c = col[e];
    float dx = posf[r*3+0] - posf[c*3+0];
    float dy = posf[r*3+1] - posf[c*3+1];
    float dz = posf[r*3+2] - posf[c*3+2];
    float ew = sqrtf(dx*dx + dy*dy + dz*dz);
    rowS[p] = r; colS[p] = c; ewS[p] = ew;
    CS[p] = 0.5f * (cosf(ew * 0.3141592653589793f) + 1.0f);
    unsigned short* o = eaS + (long)p * 4;
    for (int q = 0; q < 4; ++q)
        o[q] = (q < NB) ? f2b(eattrf[(long)e * NB + q]) : (unsigned short)0;
}

// ---------------- weight transpose to bf16 N-major ----------------------------
__global__ __launch_bounds__(256) void wtrans_kernel(
    const float* __restrict__ src, unsigned short* __restrict__ dst,
    int K, int Kpad, int N)
{
    int idx = blockIdx.x * 256 + threadIdx.x;
    if (idx >= N * Kpad) return;
    int n = idx / Kpad, k = idx - n * Kpad;
    dst[idx] = (k < K) ? f2b(src[k * N + n]) : (unsigned short)0;
}

// ---------------- tiled node GEMM [N,128]@[128,128] (fp32) --------------------
template<int MODE>
__global__ __launch_bounds__(256) void node_gemm_tiled(
    const float* __restrict__ in, const float* __restrict__ W,
    const float* __restrict__ bias, float* __restrict__ out, int N)
{
    __shared__ float in_s[32][128];
    const int t = threadIdx.x;
    const long n0 = (long)blockIdx.x * 32;
    for (int i = t; i < 32 * 128; i += 256) {
        long n = n0 + (i >> 7);
        in_s[i >> 7][i & 127] = (n < N) ? in[n * 128 + (i & 127)] : 0.f;
    }
    __syncthreads();
    const int j = t & 31, sub = t >> 5;
    const int c4 = j * 4, rb = sub * 4;
    float acc[4][4];
    float4 bv = make_float4(0.f, 0.f, 0.f, 0.f);
    if (MODE != 0) bv = *(const float4*)(bias + c4);
    #pragma unroll
    for (int i = 0; i < 4; ++i) { acc[i][0]=bv.x; acc[i][1]=bv.y; acc[i][2]=bv.z; acc[i][3]=bv.w; }
    #pragma unroll 4
    for (int k = 0; k < 128; ++k) {
        const float4 wv = *(const float4*)(W + k * 128 + c4);
        #pragma unroll
        for (int i = 0; i < 4; ++i) {
            const float a = in_s[rb + i][k];
            acc[i][0] += a * wv.x; acc[i][1] += a * wv.y;
            acc[i][2] += a * wv.z; acc[i][3] += a * wv.w;
        }
    }
    #pragma unroll
    for (int i = 0; i < 4; ++i) {
        long n = n0 + rb + i;
        if (n >= N) continue;
        float4 o;
        if (MODE == 1) {
            o.x = ssp_f(acc[i][0]); o.y = ssp_f(acc[i][1]);
            o.z = ssp_f(acc[i][2]); o.w = ssp_f(acc[i][3]);
        } else {
            o.x = acc[i][0]; o.y = acc[i][1]; o.z = acc[i][2]; o.w = acc[i][3];
        }
        if (MODE == 2) {
            float4 p = *(const float4*)(out + n * 128 + c4);
            o.x += p.x; o.y += p.y; o.z += p.z; o.w += p.w;
        }
        *(float4*)(out + n * 128 + c4) = o;
    }
}

// ---------------- MFMA edge kernel (sorted order, lean LDS) -------------------
// 32 edges/block, 4 waves, bf16 MFMA 16x16x32.
// GEMM1 A-fragments computed IN REGISTERS (gaussians per-lane, no LDS staging).
// t_b padded to 136 shorts/row; runbuf stored as bf16 (error << threshold).
__global__ __launch_bounds__(256) void edge_mfma(
    const int* __restrict__ rowS, const int* __restrict__ colS,
    const float* __restrict__ CS, const float* __restrict__ ewS,
    const unsigned short* __restrict__ eaS,
    const unsigned short* __restrict__ w1t, const float* __restrict__ b1,
    const unsigned short* __restrict__ w2t, const float* __restrict__ b2,
    const float* __restrict__ xh, float* __restrict__ agg,
    int E, int NB, int F50, float delta, float coeff)
{
    __shared__ __align__(16) short t_b[32][136];           // bf16 GEMM1 output, padded
    __shared__ unsigned short runbuf[32][136];             // bf16 messages, padded
    __shared__ int   row_s[32];
    __shared__ int   col_s[32];
    __shared__ float C_s[32];
    __shared__ int   runcol_s[32];
    __shared__ int   runstart_s[33];
    __shared__ int   nruns_s;

    const int t = threadIdx.x;
    const long p0 = (long)blockIdx.x * 32;

    if (t < 32) {
        long p = p0 + t; if (p >= E) p = E - 1;
        row_s[t] = rowS[p];
        col_s[t] = colS[p];
        C_s[t]   = (p0 + t < E) ? CS[p] : 0.f;
        // run detection: wave-coherent (all t<32 in wave 0; LDS writes above
        // complete in program order before lane 0's reads below)
        if (t == 0) {
            int nr = 0;
            for (int i = 0; i < 32; ++i) {
                if (i == 0 || col_s[i] != col_s[i - 1]) {
                    runcol_s[nr] = col_s[i];
                    runstart_s[nr] = i;
                    ++nr;
                }
            }
            runstart_s[nr] = 32;
            nruns_s = nr;
        }
    }
    __syncthreads();

    const int lane = t & 63;
    const int w    = t >> 6;
    const int colL = lane & 15;
    const int quad = lane >> 4;
    const int m0   = (w & 1) * 16;

    // this lane's A-row edge (for both GEMMs)
    long pA = p0 + m0 + colL; if (pA >= E) pA = E - 1;
    const float ew = ewS[pA];

    // ---- GEMM1: A computed in registers; B from global w1t ----
    {
        f32x4 acc[4];
        #pragma unroll
        for (int tt = 0; tt < 4; ++tt) acc[tt] = (f32x4){0.f, 0.f, 0.f, 0.f};
        #pragma unroll
        for (int ks = 0; ks < 2; ++ks) {
            const int kb = ks * 32 + quad * 8;
            union { bfrag v; unsigned short s[8]; } af;
            #pragma unroll
            for (int j = 0; j < 8; ++j) {
                const int k = kb + j;
                unsigned short u;
                if (k < NB)        u = eaS[pA * 4 + k];
                else if (k < F50) {
                    float d = ew - (float)(k - NB) * delta;
                    u = f2b(__expf(coeff * d * d));
                } else             u = 0;
                af.s[j] = u;
            }
            #pragma unroll
            for (int tt = 0; tt < 4; ++tt) {
                const int n0 = ((w >> 1) * 4 + tt) * 16;
                const bfrag b = *(const bfrag*)&w1t[(long)(n0 + colL) * 64 + kb];
                acc[tt] = __builtin_amdgcn_mfma_f32_16x16x32_bf16(af.v, b, acc[tt], 0, 0, 0);
            }
        }
        #pragma unroll
        for (int tt = 0; tt < 4; ++tt) {
            const int n0 = ((w >> 1) * 4 + tt) * 16;
            const float bcol = b1[n0 + colL];
            #pragma unroll
            for (int reg = 0; reg < 4; ++reg) {
                float v = ssp_f(acc[tt][reg] + bcol);
                t_b[m0 + quad * 4 + reg][n0 + colL] = (short)f2b(v);
            }
        }
    }
    __syncthreads();

    // ---- GEMM2: A from t_b (padded), B from global w2t; msg -> bf16 runbuf ----
    {
        f32x4 acc[4];
        #pragma unroll
        for (int tt = 0; tt < 4; ++tt) acc[tt] = (f32x4){0.f, 0.f, 0.f, 0.f};
        #pragma unroll
        for (int ks = 0; ks < 4; ++ks) {
            const bfrag a = *(const bfrag*)&t_b[m0 + colL][ks * 32 + quad * 8];
            #pragma unroll
            for (int tt = 0; tt < 4; ++tt) {
                const int n0 = ((w >> 1) * 4 + tt) * 16;
                const bfrag b = *(const bfrag*)&w2t[(long)(n0 + colL) * 128 + ks * 32 + quad * 8];
                acc[tt] = __builtin_amdgcn_mfma_f32_16x16x32_bf16(a, b, acc[tt], 0, 0, 0);
            }
        }
        const int ebase = m0 + quad * 4;
        #pragma unroll
        for (int tt = 0; tt < 4; ++tt) {
            const int n0 = ((w >> 1) * 4 + tt) * 16;
            const int cg = n0 + colL;
            const float bcol = b2[cg];
            #pragma unroll
            for (int reg = 0; reg < 4; ++reg) {
                const int e = ebase + reg;
                const float v = acc[tt][reg] + bcol;
                runbuf[e][cg] = f2b(v * C_s[e] * xh[(long)row_s[e] * 128 + cg]);
            }
        }
    }
    __syncthreads();

    // ---- per-run column reduction -> global atomic ----
    const int nr = nruns_s;
    const int cc = t & 127;
    for (int r = t >> 7; r < nr; r += 2) {
        float a = 0.f;
        const int s1 = runstart_s[r + 1];
        for (int e = runstart_s[r]; e < s1; ++e)
            a += b2f(runbuf[e][cc]);
        atomicAdd(&agg[(long)runcol_s[r] * 128 + cc], a);
    }
}

// ---------------- fp32 atomic edge kernel (fallback) --------------------------
__global__ __launch_bounds__(256) void edge_atomic(
    const float* __restrict__ posf,
    const int* __restrict__ row, const int* __restrict__ col,
    const float* __restrict__ eattrf,
    const float* __restrict__ w1, const float* __restrict__ b1,
    const float* __restrict__ w2, const float* __restrict__ b2,
    const float* __restrict__ xh, float* __restrict__ agg,
    int E, int NB, int F50, float delta, float coeff)
{
    __shared__ float ea_s[32][52];
    __shared__ float t_s[32][128];
    __shared__ int   row_s[32];
    __shared__ int   col_s[32];
    __shared__ float C_s[32];
    __shared__ float ew_s[32];

    const int t = threadIdx.x;
    const long e0 = (long)blockIdx.x * 32;

    if (t < 32) {
        long e = e0 + t; if (e >= E) e = E - 1;
        const int r = row[e], c = col[e];
        row_s[t] = r; col_s[t] = c;
        float dx = posf[r*3+0] - posf[c*3+0];
        float dy = posf[r*3+1] - posf[c*3+1];
        float dz = posf[r*3+2] - posf[c*3+2];
        float ew = sqrtf(dx*dx + dy*dy + dz*dz);
        ew_s[t] = ew;
        C_s[t]  = (e0 + t < E) ? 0.5f * (cosf(ew * 0.3141592653589793f) + 1.0f) : 0.f;
        for (int q = 0; q < NB; ++q)
            ea_s[t][q] = eattrf[e * NB + q];
    }
    __syncthreads();
    {
        const int NGS = F50 - NB;
        for (int i = t; i < 32 * NGS; i += 256) {
            const int e = i / NGS, g = i - e * NGS;
            const float d = ew_s[e] - (float)g * delta;
            ea_s[e][NB + g] = __expf(coeff * d * d);
        }
    }
    __syncthreads();

    const int j = t & 31, sub = t >> 5;
    const int c4 = j * 4, eb = sub * 4;
    float acc[4][4];
    {
        const float4 bv = *(const float4*)(b1 + c4);
        #pragma unroll
        for (int i = 0; i < 4; ++i) { acc[i][0]=bv.x; acc[i][1]=bv.y; acc[i][2]=bv.z; acc[i][3]=bv.w; }
        for (int k = 0; k < F50; ++k) {
            const float4 wv = *(const float4*)(w1 + k * 128 + c4);
            #pragma unroll
            for (int i = 0; i < 4; ++i) {
                const float a = ea_s[eb + i][k];
                acc[i][0] += a * wv.x; acc[i][1] += a * wv.y;
                acc[i][2] += a * wv.z; acc[i][3] += a * wv.w;
            }
        }
        #pragma unroll
        for (int i = 0; i < 4; ++i) {
            float4 o;
            o.x = ssp_f(acc[i][0]); o.y = ssp_f(acc[i][1]);
            o.z = ssp_f(acc[i][2]); o.w = ssp_f(acc[i][3]);
            *(float4*)&t_s[eb + i][c4] = o;
        }
    }
    __syncthreads();
    {
        const float4 bv = *(const float4*)(b2 + c4);
        #pragma unroll
        for (int i = 0; i < 4; ++i) { acc[i][0]=bv.x; acc[i][1]=bv.y; acc[i][2]=bv.z; acc[i][3]=bv.w; }
        #pragma unroll 4
        for (int k = 0; k < 128; ++k) {
            const float4 wv = *(const float4*)(w2 + k * 128 + c4);
            #pragma unroll
            for (int i = 0; i < 4; ++i) {
                const float a = t_s[eb + i][k];
                acc[i][0] += a * wv.x; acc[i][1] += a * wv.y;
                acc[i][2] += a * wv.z; acc[i][3] += a * wv.w;
            }
        }
    }
    #pragma unroll
    for (int i = 0; i < 4; ++i) {
        const int e = eb + i;
        if (e0 + e >= E) continue;
        const float Ce = C_s[e];
        const float4 xv = *(const float4*)(xh + (long)row_s[e] * 128 + c4);
        float* ag = agg + (long)col_s[e] * 128 + c4;
        atomicAdd(ag + 0, acc[i][0] * Ce * xv.x);
        atomicAdd(ag + 1, acc[i][1] * Ce * xv.y);
        atomicAdd(ag + 2, acc[i][2] * Ce * xv.z);
        atomicAdd(ag + 3, acc[i][3] * Ce * xv.w);
    }
}

// ---------------- readout ------------------------------------------------------
__global__ __launch_bounds__(128) void readout_simple(
    const float* __restrict__ h,
    const float* __restrict__ o1w, const float* __restrict__ o1b,
    const float* __restrict__ o2w, const float* __restrict__ o2b,
    const int* __restrict__ batch, float* __restrict__ accb)
{
    __shared__ float hr[128];
    __shared__ float vv[64];
    const int n = blockIdx.x;
    const int t = threadIdx.x;
    hr[t] = h[(long)n * 128 + t];
    __syncthreads();
    if (t < 64) {
        float a = o1b[t];
        #pragma unroll 8
        for (int k = 0; k < 128; ++k)
            a = fmaf(hr[k], o1w[k * 64 + t], a);
        vv[t] = ssp_f(a) * o2w[t];
    }
    __syncthreads();
    if (t < 32) vv[t] += vv[t + 32];
    __syncthreads();
    if (t < 16) vv[t] += vv[t + 16];
    __syncthreads();
    if (t < 8)  vv[t] += vv[t + 8];
    __syncthreads();
    if (t < 4)  vv[t] += vv[t + 4];
    __syncthreads();
    if (t < 2)  vv[t] += vv[t + 2];
    __syncthreads();
    if (t == 0) atomicAdd(&accb[batch[n]], vv[0] + vv[1] + o2b[0]);
}

// output is FLOAT32 (verified round 11)
__global__ void finalize_kernel(const float* __restrict__ accb,
                                float* __restrict__ out, int B)
{
    int t = blockIdx.x * 256 + threadIdx.x;
    if (t < B) out[t] = accb[t];
}

// ---------------- launch -------------------------------------------------------
extern "C" void kernel_launch(void* const* d_in, const int* in_sizes, int n_in,
                              void* d_out, int out_size, void* d_ws, size_t ws_size,
                              hipStream_t stream)
{
    const int N   = in_sizes[0];
    const int E   = in_sizes[3] / 2;
    const int B   = out_size;
    const int H   = 128;
    const int L   = in_sizes[7] / H;
    const int NB  = in_sizes[4] / E;
    const int F50 = in_sizes[6] / (L * H);
    const int NGS = F50 - NB;
    const float delta = 10.0f / (float)(NGS - 1);
    const float coeff = -0.5f / (delta * delta);

    const int fidx[16] = {1, 4, 5, 6, 7, 8, 9, 10, 11, 12, 13, 14, 15, 16, 17, 18};
    long foff[17]; foff[0] = 0;
    for (int i = 0; i < 16; ++i) foff[i + 1] = foff[i] + in_sizes[fidx[i]];

    float* F = (float*)d_ws;
    long base = (foff[16] + 3) & ~3L;
    float* h    = F + base;
    float* xh   = h + (long)N * H;
    float* agg  = xh + (long)N * H;
    float* accb = agg + (long)N * H;
    int*   flag  = (int*)(accb + ((B + 3) & ~3));
    int*   iflag = flag + 1;
    int*   zi     = flag + 4;
    int*   batchi = zi + N;
    int*   eidxi  = batchi + N;
    int*   count  = eidxi + 2 * E;
    int*   rowptr = count + N;
    int*   next   = rowptr + N + 1;
    int*   slot   = next + N;
    int*   perm   = slot + E;
    int*   rowS   = perm + E;
    int*   colS   = rowS + E;
    float* CS     = (float*)(colS + E);
    float* ewS    = CS + E;
    unsigned short* eaS = (unsigned short*)(ewS + E);      // 4E ushorts
    unsigned short* w1t = eaS + 4L * E;                    // L*128*64
    unsigned short* w2t = w1t + (long)L * 128 * 64;        // L*128*128
    long used_bytes = (long)((char*)(w2t + (long)L * 128 * 128) - (char*)d_ws);
    const bool use_fast = (used_bytes <= (long)ws_size) && (F50 <= 64) && (NB <= 4);

    sniff_kernel<<<1, 256, 0, stream>>>((const unsigned int*)d_in[5], flag);
    sniff_int_kernel<<<1, 128, 0, stream>>>((const unsigned int*)d_in[0], iflag);

    for (int i = 0; i < 16; ++i) {
        int n = in_sizes[fidx[i]];
        convert_kernel<<<(n + 255) / 256, 256, 0, stream>>>(d_in[fidx[i]], F + foff[i], n, flag);
    }
    convert_int_kernel<<<(N + 255) / 256, 256, 0, stream>>>(d_in[0], zi, N, iflag);
    convert_int_kernel<<<(N + 255) / 256, 256, 0, stream>>>(d_in[2], batchi, N, iflag);
    convert_int_kernel<<<(2 * E + 255) / 256, 256, 0, stream>>>(d_in[3], eidxi, 2 * E, iflag);

    const float* posf   = F + foff[0];
    const float* eattrf = F + foff[1];
    const float* embf   = F + foff[2];
    const float* w1   = F + foff[3];  const float* b1   = F + foff[4];
    const float* w2   = F + foff[5];  const float* b2   = F + foff[6];
    const float* cf1  = F + foff[7];  const float* cf2  = F + foff[8];
    const float* cf2b = F + foff[9];  const float* lin  = F + foff[10];
    const float* linb = F + foff[11]; const float* o1   = F + foff[12];
    const float* o1b  = F + foff[13]; const float* o2   = F + foff[14];
    const float* o2b  = F + foff[15];

    if (use_fast) {
        zero_int_kernel<<<(N + 255) / 256, 256, 0, stream>>>(count, N);
        hist_kernel<<<(E + 255) / 256, 256, 0, stream>>>(eidxi + E, count, E);
        scan_kernel<<<1, 256, 0, stream>>>(count, rowptr, next, N);
        slot_kernel<<<(E + 255) / 256, 256, 0, stream>>>(eidxi + E, next, slot, E);
        perm_kernel<<<(E + 255) / 256, 256, 0, stream>>>(slot, perm, E);
        prep_edges_kernel<<<(E + 255) / 256, 256, 0, stream>>>(
            posf, eidxi, eidxi + E, eattrf, perm, rowS, colS, CS, ewS, eaS, E, NB);
        for (int l = 0; l < L; ++l) {
            wtrans_kernel<<<(128 * 64 + 255) / 256, 256, 0, stream>>>(
                w1 + (long)l * F50 * H, w1t + (long)l * 128 * 64, F50, 64, 128);
            wtrans_kernel<<<(128 * 128 + 255) / 256, 256, 0, stream>>>(
                w2 + (long)l * H * H, w2t + (long)l * 128 * 128, 128, 128, 128);
        }
    }

    embed_kernel<<<(N * H + 255) / 256, 256, 0, stream>>>(zi, embf, h, N * H);
    hipMemsetAsync(accb, 0, (size_t)B * sizeof(float), stream);

    const int ngemm = (N + 31) / 32;
    const int nedge = (E + 31) / 32;
    for (int l = 0; l < L; ++l) {
        hipMemsetAsync(agg, 0, (size_t)N * H * sizeof(float), stream);
        node_gemm_tiled<0><<<ngemm, 256, 0, stream>>>(h, cf1 + (long)l * H * H, nullptr, xh, N);
        if (use_fast) {
            edge_mfma<<<nedge, 256, 0, stream>>>(
                rowS, colS, CS, ewS, eaS,
                w1t + (long)l * 128 * 64, b1 + (long)l * H,
                w2t + (long)l * 128 * 128, b2 + (long)l * H,
                xh, agg, E, NB, F50, delta, coeff);
        } else {
            edge_atomic<<<nedge, 256, 0, stream>>>(
                posf, eidxi, eidxi + E, eattrf,
                w1 + (long)l * F50 * H, b1 + (long)l * H,
                w2 + (long)l * H * H,  b2 + (long)l * H,
                xh, agg, E, NB, F50, delta, coeff);
        }
        node_gemm_tiled<1><<<ngemm, 256, 0, stream>>>(agg, cf2 + (long)l * H * H, cf2b + (long)l * H, xh, N);
        node_gemm_tiled<2><<<ngemm, 256, 0, stream>>>(xh, lin + (long)l * H * H, linb + (long)l * H, h, N);
    }

    readout_simple<<<N, 128, 0, stream>>>(h, o1, o1b, o2, o2b, batchi, accb);
    finalize_kernel<<<(B + 255) / 256, 256, 0, stream>>>(accb, (float*)d_out, B);
}

// Round 18
// 1596.239 us; speedup vs baseline: 1.0239x; 1.0239x over previous
//
#include <hip/hip_runtime.h>
#include <hip/hip_bf16.h>

typedef __attribute__((ext_vector_type(8))) short bfrag;
typedef __attribute__((ext_vector_type(4))) float f32x4;

// fast shifted softplus: __logf/__expf intrinsics (rel err ~2^-21, threshold 2.3e-2)
__device__ __forceinline__ float ssp_f(float x) {
    return fmaxf(x, 0.f) + __logf(1.f + __expf(-fabsf(x))) - 0.6931471805599453f;
}

__device__ __forceinline__ unsigned short f2b(float x) {
    __hip_bfloat16 h = __float2bfloat16(x);
    return *(unsigned short*)&h;
}

__device__ __forceinline__ float b2f(unsigned short u) {
    unsigned int w = ((unsigned int)u) << 16;
    return *(float*)&w;
}

// ---------------- float dtype sniffer ----------------------------------------
__global__ void sniff_kernel(const unsigned int* __restrict__ raw, int* __restrict__ flag)
{
    __shared__ int cnt[256];
    const int t = threadIdx.x;
    unsigned int w = raw[t];
    unsigned int e = (w >> 7) & 0xFFu;
    cnt[t] = (e >= 100u && e <= 135u) ? 1 : 0;
    __syncthreads();
    for (int s = 128; s > 0; s >>= 1) {
        if (t < s) cnt[t] += cnt[t + s];
        __syncthreads();
    }
    if (t == 0) *flag = (cnt[0] >= 160) ? 1 : 0;   // 1 = floats are bf16
}

// ---------------- int width sniffer -------------------------------------------
__global__ void sniff_int_kernel(const unsigned int* __restrict__ z, int* __restrict__ iflag)
{
    __shared__ int cnt[128];
    const int t = threadIdx.x;
    cnt[t] = (z[2 * t + 1] == 0u) ? 1 : 0;
    __syncthreads();
    for (int s = 64; s > 0; s >>= 1) {
        if (t < s) cnt[t] += cnt[t + s];
        __syncthreads();
    }
    if (t == 0) *iflag = (cnt[0] >= 126) ? 1 : 0;  // 1 = ints are int64
}

// ---------------- fused convert of all 16 float tensors -----------------------
struct Cvt16 {
    const void* src[16];
    long off[17];
};

__global__ __launch_bounds__(256) void convert_fused_kernel(
    Cvt16 args, float* __restrict__ F, long total, const int* __restrict__ flag)
{
    long i = (long)blockIdx.x * 256 + threadIdx.x;
    if (i >= total) return;
    int lo = 0, hi = 16;
    while (hi - lo > 1) {
        int mid = (lo + hi) >> 1;
        if (i >= args.off[mid]) lo = mid; else hi = mid;
    }
    long loc = i - args.off[lo];
    if (*flag) F[i] = __bfloat162float(((const __hip_bfloat16*)args.src[lo])[loc]);
    else       F[i] = ((const float*)args.src[lo])[loc];
}

__global__ __launch_bounds__(256) void convert_int_kernel(
    const void* __restrict__ src, int* __restrict__ dst, int n,
    const int* __restrict__ iflag)
{
    int i = blockIdx.x * 256 + threadIdx.x;
    if (i >= n) return;
    if (*iflag) dst[i] = (int)(((const long long*)src)[i]);
    else        dst[i] = ((const int*)src)[i];
}

// ---------------- node embedding gather ---------------------------------------
__global__ __launch_bounds__(256) void embed_kernel(
    const int* __restrict__ z, const float* __restrict__ embf,
    float* __restrict__ h, int NH)
{
    int idx = blockIdx.x * 256 + threadIdx.x;
    if (idx >= NH) return;
    h[idx] = embf[z[idx >> 7] * 128 + (idx & 127)];
}

// ---------------- CSR build ----------------------------------------------------
__global__ __launch_bounds__(256) void zero_int_kernel(int* p, int n)
{
    int i = blockIdx.x * 256 + threadIdx.x;
    if (i < n) p[i] = 0;
}

__global__ __launch_bounds__(256) void hist_kernel(const int* __restrict__ col,
                                                   int* __restrict__ count, int E)
{
    int e = blockIdx.x * 256 + threadIdx.x;
    if (e < E) atomicAdd(&count[col[e]], 1);
}

__global__ __launch_bounds__(256) void scan_kernel(const int* __restrict__ count,
                                                   int* __restrict__ rowptr,
                                                   int* __restrict__ next, int N)
{
    __shared__ int part[256];
    const int t = threadIdx.x;
    const int chunk = (N + 255) / 256;
    const int lo = t * chunk, hi = min(lo + chunk, N);
    int s = 0;
    for (int i = lo; i < hi; ++i) s += count[i];
    part[t] = s;
    __syncthreads();
    if (t == 0) {
        int run = 0;
        for (int i = 0; i < 256; ++i) { int v = part[i]; part[i] = run; run += v; }
        rowptr[N] = run;
    }
    __syncthreads();
    int run = part[t];
    for (int i = lo; i < hi; ++i) {
        rowptr[i] = run; next[i] = run;
        run += count[i];
    }
}

__global__ __launch_bounds__(256) void slot_kernel(const int* __restrict__ col,
                                                   int* __restrict__ next,
                                                   int* __restrict__ slot, int E)
{
    int e = blockIdx.x * 256 + threadIdx.x;
    if (e < E) slot[e] = atomicAdd(&next[col[e]], 1);
}

__global__ __launch_bounds__(256) void perm_kernel(const int* __restrict__ slot,
                                                   int* __restrict__ perm, int E)
{
    int e = blockIdx.x * 256 + threadIdx.x;
    if (e < E) perm[slot[e]] = e;
}

// ---------------- pre-permute edge data into sorted order ---------------------
__global__ __launch_bounds__(256) void prep_edges_kernel(
    const float* __restrict__ posf, const int* __restrict__ row,
    const int* __restrict__ col, const float* __restrict__ eattrf,
    const int* __restrict__ perm,
    int* __restrict__ rowS, int* __restrict__ colS,
    float* __restrict__ CS, float* __restrict__ ewS,
    unsigned short* __restrict__ eaS, int E, int NB)
{
    int p = blockIdx.x * 256 + threadIdx.x;
    if (p >= E) return;
    const int e = perm[p];
    const int r = row[e], c = col[e];
    float dx = posf[r*3+0] - posf[c*3+0];
    float dy = posf[r*3+1] - posf[c*3+1];
    float dz = posf[r*3+2] - posf[c*3+2];
    float ew = sqrtf(dx*dx + dy*dy + dz*dz);
    rowS[p] = r; colS[p] = c; ewS[p] = ew;
    CS[p] = 0.5f * (cosf(ew * 0.3141592653589793f) + 1.0f);
    unsigned short* o = eaS + (long)p * 4;
    for (int q = 0; q < 4; ++q)
        o[q] = (q < NB) ? f2b(eattrf[(long)e * NB + q]) : (unsigned short)0;
}

// ---------------- weight transpose to bf16 N-major ----------------------------
__global__ __launch_bounds__(256) void wtrans_kernel(
    const float* __restrict__ src, unsigned short* __restrict__ dst,
    int K, int Kpad, int N)
{
    int idx = blockIdx.x * 256 + threadIdx.x;
    if (idx >= N * Kpad) return;
    int n = idx / Kpad, k = idx - n * Kpad;
    dst[idx] = (k < K) ? f2b(src[k * N + n]) : (unsigned short)0;
}

// ---------------- tiled node GEMM [N,128]@[128,128] (fp32) --------------------
template<int MODE>
__global__ __launch_bounds__(256) void node_gemm_tiled(
    const float* __restrict__ in, const float* __restrict__ W,
    const float* __restrict__ bias, float* __restrict__ out, int N)
{
    __shared__ float in_s[32][128];
    const int t = threadIdx.x;
    const long n0 = (long)blockIdx.x * 32;
    for (int i = t; i < 32 * 128; i += 256) {
        long n = n0 + (i >> 7);
        in_s[i >> 7][i & 127] = (n < N) ? in[n * 128 + (i & 127)] : 0.f;
    }
    __syncthreads();
    const int j = t & 31, sub = t >> 5;
    const int c4 = j * 4, rb = sub * 4;
    float acc[4][4];
    float4 bv = make_float4(0.f, 0.f, 0.f, 0.f);
    if (MODE != 0) bv = *(const float4*)(bias + c4);
    #pragma unroll
    for (int i = 0; i < 4; ++i) { acc[i][0]=bv.x; acc[i][1]=bv.y; acc[i][2]=bv.z; acc[i][3]=bv.w; }
    #pragma unroll 4
    for (int k = 0; k < 128; ++k) {
        const float4 wv = *(const float4*)(W + k * 128 + c4);
        #pragma unroll
        for (int i = 0; i < 4; ++i) {
            const float a = in_s[rb + i][k];
            acc[i][0] += a * wv.x; acc[i][1] += a * wv.y;
            acc[i][2] += a * wv.z; acc[i][3] += a * wv.w;
        }
    }
    #pragma unroll
    for (int i = 0; i < 4; ++i) {
        long n = n0 + rb + i;
        if (n >= N) continue;
        float4 o;
        if (MODE == 1) {
            o.x = ssp_f(acc[i][0]); o.y = ssp_f(acc[i][1]);
            o.z = ssp_f(acc[i][2]); o.w = ssp_f(acc[i][3]);
        } else {
            o.x = acc[i][0]; o.y = acc[i][1]; o.z = acc[i][2]; o.w = acc[i][3];
        }
        if (MODE == 2) {
            float4 p = *(const float4*)(out + n * 128 + c4);
            o.x += p.x; o.y += p.y; o.z += p.z; o.w += p.w;
        }
        *(float4*)(out + n * 128 + c4) = o;
    }
}

// ---------------- MFMA edge kernel (sorted order) -----------------------------
// r16 structure (ea_b LDS staging) + r17's LDS diet: ea_b padded to 72,
// t_b padded to 136, runbuf bf16. LDS ~22.7 KB -> 7 blocks/CU.
__global__ __launch_bounds__(256) void edge_mfma(
    const int* __restrict__ rowS, const int* __restrict__ colS,
    const float* __restrict__ CS, const float* __restrict__ ewS,
    const unsigned short* __restrict__ eaS,
    const unsigned short* __restrict__ w1t, const float* __restrict__ b1,
    const unsigned short* __restrict__ w2t, const float* __restrict__ b2,
    const float* __restrict__ xh, float* __restrict__ agg,
    int E, int NB, int F50, float delta, float coeff)
{
    __shared__ __align__(16) short ea_b[32][72];           // bf16 input, K<=64 used, padded
    __shared__ __align__(16) short t_b[32][136];           // bf16 GEMM1 output, padded
    __shared__ unsigned short runbuf[32][136];             // bf16 messages, padded
    __shared__ int   row_s[32];
    __shared__ int   col_s[32];
    __shared__ float C_s[32];
    __shared__ float ew_s[32];
    __shared__ int   runcol_s[32];
    __shared__ int   runstart_s[33];
    __shared__ int   nruns_s;

    const int t = threadIdx.x;
    const long p0 = (long)blockIdx.x * 32;

    if (t < 32) {
        long p = p0 + t; if (p >= E) p = E - 1;
        row_s[t] = rowS[p];
        col_s[t] = colS[p];
        C_s[t]   = (p0 + t < E) ? CS[p] : 0.f;
        ew_s[t]  = ewS[p];
        if (t == 0) {
            // same wave: LDS writes above are visible in program order
            int nr = 0;
            for (int i = 0; i < 32; ++i) {
                if (i == 0 || col_s[i] != col_s[i - 1]) {
                    runcol_s[nr] = col_s[i];
                    runstart_s[nr] = i;
                    ++nr;
                }
            }
            runstart_s[nr] = 32;
            nruns_s = nr;
        }
    }
    __syncthreads();
    // fill ea_b (bf16): [0,NB) from eaS, [NB,F50) gaussians, rest zero
    for (int i = t; i < 32 * 64; i += 256) {
        const int e = i >> 6, k = i & 63;
        long p = p0 + e; if (p >= E) p = E - 1;
        unsigned short v;
        if (k < NB)        v = eaS[p * 4 + k];
        else if (k < F50) {
            float d = ew_s[e] - (float)(k - NB) * delta;
            v = f2b(__expf(coeff * d * d));
        } else             v = 0;
        ea_b[e][k] = (short)v;
    }
    __syncthreads();

    const int lane = t & 63;
    const int w    = t >> 6;
    const int colL = lane & 15;
    const int quad = lane >> 4;
    const int m0   = (w & 1) * 16;

    // ---- GEMM1: ea_b @ w1t -> ssp -> t_b (bf16) ----
    {
        f32x4 acc[4];
        #pragma unroll
        for (int tt = 0; tt < 4; ++tt) acc[tt] = (f32x4){0.f, 0.f, 0.f, 0.f};
        #pragma unroll
        for (int ks = 0; ks < 2; ++ks) {
            const bfrag a = *(const bfrag*)&ea_b[m0 + colL][ks * 32 + quad * 8];
            #pragma unroll
            for (int tt = 0; tt < 4; ++tt) {
                const int n0 = ((w >> 1) * 4 + tt) * 16;
                const bfrag b = *(const bfrag*)&w1t[(long)(n0 + colL) * 64 + ks * 32 + quad * 8];
                acc[tt] = __builtin_amdgcn_mfma_f32_16x16x32_bf16(a, b, acc[tt], 0, 0, 0);
            }
        }
        #pragma unroll
        for (int tt = 0; tt < 4; ++tt) {
            const int n0 = ((w >> 1) * 4 + tt) * 16;
            const float bcol = b1[n0 + colL];
            #pragma unroll
            for (int reg = 0; reg < 4; ++reg) {
                float v = ssp_f(acc[tt][reg] + bcol);
                t_b[m0 + quad * 4 + reg][n0 + colL] = (short)f2b(v);
            }
        }
    }
    __syncthreads();

    // ---- GEMM2: t_b @ w2t; msg -> bf16 runbuf ----
    {
        f32x4 acc[4];
        #pragma unroll
        for (int tt = 0; tt < 4; ++tt) acc[tt] = (f32x4){0.f, 0.f, 0.f, 0.f};
        #pragma unroll
        for (int ks = 0; ks < 4; ++ks) {
            const bfrag a = *(const bfrag*)&t_b[m0 + colL][ks * 32 + quad * 8];
            #pragma unroll
            for (int tt = 0; tt < 4; ++tt) {
                const int n0 = ((w >> 1) * 4 + tt) * 16;
                const bfrag b = *(const bfrag*)&w2t[(long)(n0 + colL) * 128 + ks * 32 + quad * 8];
                acc[tt] = __builtin_amdgcn_mfma_f32_16x16x32_bf16(a, b, acc[tt], 0, 0, 0);
            }
        }
        const int ebase = m0 + quad * 4;
        #pragma unroll
        for (int tt = 0; tt < 4; ++tt) {
            const int n0 = ((w >> 1) * 4 + tt) * 16;
            const int cg = n0 + colL;
            const float bcol = b2[cg];
            #pragma unroll
            for (int reg = 0; reg < 4; ++reg) {
                const int e = ebase + reg;
                const float v = acc[tt][reg] + bcol;
                runbuf[e][cg] = f2b(v * C_s[e] * xh[(long)row_s[e] * 128 + cg]);
            }
        }
    }
    __syncthreads();

    // ---- per-run column reduction -> global atomic ----
    const int nr = nruns_s;
    const int cc = t & 127;
    for (int r = t >> 7; r < nr; r += 2) {
        float a = 0.f;
        const int s1 = runstart_s[r + 1];
        for (int e = runstart_s[r]; e < s1; ++e)
            a += b2f(runbuf[e][cc]);
        atomicAdd(&agg[(long)runcol_s[r] * 128 + cc], a);
    }
}

// ---------------- fp32 atomic edge kernel (fallback) --------------------------
__global__ __launch_bounds__(256) void edge_atomic(
    const float* __restrict__ posf,
    const int* __restrict__ row, const int* __restrict__ col,
    const float* __restrict__ eattrf,
    const float* __restrict__ w1, const float* __restrict__ b1,
    const float* __restrict__ w2, const float* __restrict__ b2,
    const float* __restrict__ xh, float* __restrict__ agg,
    int E, int NB, int F50, float delta, float coeff)
{
    __shared__ float ea_s[32][52];
    __shared__ float t_s[32][128];
    __shared__ int   row_s[32];
    __shared__ int   col_s[32];
    __shared__ float C_s[32];
    __shared__ float ew_s[32];

    const int t = threadIdx.x;
    const long e0 = (long)blockIdx.x * 32;

    if (t < 32) {
        long e = e0 + t; if (e >= E) e = E - 1;
        const int r = row[e], c = col[e];
        row_s[t] = r; col_s[t] = c;
        float dx = posf[r*3+0] - posf[c*3+0];
        float dy = posf[r*3+1] - posf[c*3+1];
        float dz = posf[r*3+2] - posf[c*3+2];
        float ew = sqrtf(dx*dx + dy*dy + dz*dz);
        ew_s[t] = ew;
        C_s[t]  = (e0 + t < E) ? 0.5f * (cosf(ew * 0.3141592653589793f) + 1.0f) : 0.f;
        for (int q = 0; q < NB; ++q)
            ea_s[t][q] = eattrf[e * NB + q];
    }
    __syncthreads();
    {
        const int NGS = F50 - NB;
        for (int i = t; i < 32 * NGS; i += 256) {
            const int e = i / NGS, g = i - e * NGS;
            const float d = ew_s[e] - (float)g * delta;
            ea_s[e][NB + g] = __expf(coeff * d * d);
        }
    }
    __syncthreads();

    const int j = t & 31, sub = t >> 5;
    const int c4 = j * 4, eb = sub * 4;
    float acc[4][4];
    {
        const float4 bv = *(const float4*)(b1 + c4);
        #pragma unroll
        for (int i = 0; i < 4; ++i) { acc[i][0]=bv.x; acc[i][1]=bv.y; acc[i][2]=bv.z; acc[i][3]=bv.w; }
        for (int k = 0; k < F50; ++k) {
            const float4 wv = *(const float4*)(w1 + k * 128 + c4);
            #pragma unroll
            for (int i = 0; i < 4; ++i) {
                const float a = ea_s[eb + i][k];
                acc[i][0] += a * wv.x; acc[i][1] += a * wv.y;
                acc[i][2] += a * wv.z; acc[i][3] += a * wv.w;
            }
        }
        #pragma unroll
        for (int i = 0; i < 4; ++i) {
            float4 o;
            o.x = ssp_f(acc[i][0]); o.y = ssp_f(acc[i][1]);
            o.z = ssp_f(acc[i][2]); o.w = ssp_f(acc[i][3]);
            *(float4*)&t_s[eb + i][c4] = o;
        }
    }
    __syncthreads();
    {
        const float4 bv = *(const float4*)(b2 + c4);
        #pragma unroll
        for (int i = 0; i < 4; ++i) { acc[i][0]=bv.x; acc[i][1]=bv.y; acc[i][2]=bv.z; acc[i][3]=bv.w; }
        #pragma unroll 4
        for (int k = 0; k < 128; ++k) {
            const float4 wv = *(const float4*)(w2 + k * 128 + c4);
            #pragma unroll
            for (int i = 0; i < 4; ++i) {
                const float a = t_s[eb + i][k];
                acc[i][0] += a * wv.x; acc[i][1] += a * wv.y;
                acc[i][2] += a * wv.z; acc[i][3] += a * wv.w;
            }
        }
    }
    #pragma unroll
    for (int i = 0; i < 4; ++i) {
        const int e = eb + i;
        if (e0 + e >= E) continue;
        const float Ce = C_s[e];
        const float4 xv = *(const float4*)(xh + (long)row_s[e] * 128 + c4);
        float* ag = agg + (long)col_s[e] * 128 + c4;
        atomicAdd(ag + 0, acc[i][0] * Ce * xv.x);
        atomicAdd(ag + 1, acc[i][1] * Ce * xv.y);
        atomicAdd(ag + 2, acc[i][2] * Ce * xv.z);
        atomicAdd(ag + 3, acc[i][3] * Ce * xv.w);
    }
}

// ---------------- readout ------------------------------------------------------
__global__ __launch_bounds__(128) void readout_simple(
    const float* __restrict__ h,
    const float* __restrict__ o1w, const float* __restrict__ o1b,
    const float* __restrict__ o2w, const float* __restrict__ o2b,
    const int* __restrict__ batch, float* __restrict__ accb)
{
    __shared__ float hr[128];
    __shared__ float vv[64];
    const int n = blockIdx.x;
    const int t = threadIdx.x;
    hr[t] = h[(long)n * 128 + t];
    __syncthreads();
    if (t < 64) {
        float a = o1b[t];
        #pragma unroll 8
        for (int k = 0; k < 128; ++k)
            a = fmaf(hr[k], o1w[k * 64 + t], a);
        vv[t] = ssp_f(a) * o2w[t];
    }
    __syncthreads();
    if (t < 32) vv[t] += vv[t + 32];
    __syncthreads();
    if (t < 16) vv[t] += vv[t + 16];
    __syncthreads();
    if (t < 8)  vv[t] += vv[t + 8];
    __syncthreads();
    if (t < 4)  vv[t] += vv[t + 4];
    __syncthreads();
    if (t < 2)  vv[t] += vv[t + 2];
    __syncthreads();
    if (t == 0) atomicAdd(&accb[batch[n]], vv[0] + vv[1] + o2b[0]);
}

// output is FLOAT32 (verified round 11)
__global__ void finalize_kernel(const float* __restrict__ accb,
                                float* __restrict__ out, int B)
{
    int t = blockIdx.x * 256 + threadIdx.x;
    if (t < B) out[t] = accb[t];
}

// ---------------- launch -------------------------------------------------------
extern "C" void kernel_launch(void* const* d_in, const int* in_sizes, int n_in,
                              void* d_out, int out_size, void* d_ws, size_t ws_size,
                              hipStream_t stream)
{
    const int N   = in_sizes[0];
    const int E   = in_sizes[3] / 2;
    const int B   = out_size;
    const int H   = 128;
    const int L   = in_sizes[7] / H;
    const int NB  = in_sizes[4] / E;
    const int F50 = in_sizes[6] / (L * H);
    const int NGS = F50 - NB;
    const float delta = 10.0f / (float)(NGS - 1);
    const float coeff = -0.5f / (delta * delta);

    const int fidx[16] = {1, 4, 5, 6, 7, 8, 9, 10, 11, 12, 13, 14, 15, 16, 17, 18};
    Cvt16 cv;
    cv.off[0] = 0;
    for (int i = 0; i < 16; ++i) {
        cv.src[i] = d_in[fidx[i]];
        cv.off[i + 1] = cv.off[i] + in_sizes[fidx[i]];
    }
    const long ftot = cv.off[16];

    float* F = (float*)d_ws;
    long base = (ftot + 3) & ~3L;
    float* h    = F + base;
    float* xh   = h + (long)N * H;
    float* agg  = xh + (long)N * H;
    float* accb = agg + (long)N * H;
    int*   flag  = (int*)(accb + ((B + 3) & ~3));
    int*   iflag = flag + 1;
    int*   zi     = flag + 4;
    int*   batchi = zi + N;
    int*   eidxi  = batchi + N;
    int*   count  = eidxi + 2 * E;
    int*   rowptr = count + N;
    int*   next   = rowptr + N + 1;
    int*   slot   = next + N;
    int*   perm   = slot + E;
    int*   rowS   = perm + E;
    int*   colS   = rowS + E;
    float* CS     = (float*)(colS + E);
    float* ewS    = CS + E;
    unsigned short* eaS = (unsigned short*)(ewS + E);      // 4E ushorts
    unsigned short* w1t = eaS + 4L * E;                    // L*128*64
    unsigned short* w2t = w1t + (long)L * 128 * 64;        // L*128*128
    long used_bytes = (long)((char*)(w2t + (long)L * 128 * 128) - (char*)d_ws);
    const bool use_fast = (used_bytes <= (long)ws_size) && (F50 <= 64) && (NB <= 4);

    sniff_kernel<<<1, 256, 0, stream>>>((const unsigned int*)d_in[5], flag);
    sniff_int_kernel<<<1, 128, 0, stream>>>((const unsigned int*)d_in[0], iflag);

    convert_fused_kernel<<<(int)((ftot + 255) / 256), 256, 0, stream>>>(cv, F, ftot, flag);
    convert_int_kernel<<<(N + 255) / 256, 256, 0, stream>>>(d_in[0], zi, N, iflag);
    convert_int_kernel<<<(N + 255) / 256, 256, 0, stream>>>(d_in[2], batchi, N, iflag);
    convert_int_kernel<<<(2 * E + 255) / 256, 256, 0, stream>>>(d_in[3], eidxi, 2 * E, iflag);

    const float* posf   = F + cv.off[0];
    const float* eattrf = F + cv.off[1];
    const float* embf   = F + cv.off[2];
    const float* w1   = F + cv.off[3];  const float* b1   = F + cv.off[4];
    const float* w2   = F + cv.off[5];  const float* b2   = F + cv.off[6];
    const float* cf1  = F + cv.off[7];  const float* cf2  = F + cv.off[8];
    const float* cf2b = F + cv.off[9];  const float* lin  = F + cv.off[10];
    const float* linb = F + cv.off[11]; const float* o1   = F + cv.off[12];
    const float* o1b  = F + cv.off[13]; const float* o2   = F + cv.off[14];
    const float* o2b  = F + cv.off[15];

    if (use_fast) {
        zero_int_kernel<<<(N + 255) / 256, 256, 0, stream>>>(count, N);
        hist_kernel<<<(E + 255) / 256, 256, 0, stream>>>(eidxi + E, count, E);
        scan_kernel<<<1, 256, 0, stream>>>(count, rowptr, next, N);
        slot_kernel<<<(E + 255) / 256, 256, 0, stream>>>(eidxi + E, next, slot, E);
        perm_kernel<<<(E + 255) / 256, 256, 0, stream>>>(slot, perm, E);
        prep_edges_kernel<<<(E + 255) / 256, 256, 0, stream>>>(
            posf, eidxi, eidxi + E, eattrf, perm, rowS, colS, CS, ewS, eaS, E, NB);
        for (int l = 0; l < L; ++l) {
            wtrans_kernel<<<(128 * 64 + 255) / 256, 256, 0, stream>>>(
                w1 + (long)l * F50 * H, w1t + (long)l * 128 * 64, F50, 64, 128);
            wtrans_kernel<<<(128 * 128 + 255) / 256, 256, 0, stream>>>(
                w2 + (long)l * H * H, w2t + (long)l * 128 * 128, 128, 128, 128);
        }
    }

    embed_kernel<<<(N * H + 255) / 256, 256, 0, stream>>>(zi, embf, h, N * H);
    hipMemsetAsync(accb, 0, (size_t)B * sizeof(float), stream);

    const int ngemm = (N + 31) / 32;
    const int nedge = (E + 31) / 32;
    for (int l = 0; l < L; ++l) {
        hipMemsetAsync(agg, 0, (size_t)N * H * sizeof(float), stream);
        node_gemm_tiled<0><<<ngemm, 256, 0, stream>>>(h, cf1 + (long)l * H * H, nullptr, xh, N);
        if (use_fast) {
            edge_mfma<<<nedge, 256, 0, stream>>>(
                rowS, colS, CS, ewS, eaS,
                w1t + (long)l * 128 * 64, b1 + (long)l * H,
                w2t + (long)l * 128 * 128, b2 + (long)l * H,
                xh, agg, E, NB, F50, delta, coeff);
        } else {
            edge_atomic<<<nedge, 256, 0, stream>>>(
                posf, eidxi, eidxi + E, eattrf,
                w1 + (long)l * F50 * H, b1 + (long)l * H,
                w2 + (long)l * H * H,  b2 + (long)l * H,
                xh, agg, E, NB, F50, delta, coeff);
        }
        node_gemm_tiled<1><<<ngemm, 256, 0, stream>>>(agg, cf2 + (long)l * H * H, cf2b + (long)l * H, xh, N);
        node_gemm_tiled<2><<<ngemm, 256, 0, stream>>>(xh, lin + (long)l * H * H, linb + (long)l * H, h, N);
    }

    readout_simple<<<N, 128, 0, stream>>>(h, o1, o1b, o2, o2b, batchi, accb);
    finalize_kernel<<<(B + 255) / 256, 256, 0, stream>>>(accb, (float*)d_out, B);
}

// Round 19
// 1455.365 us; speedup vs baseline: 1.1230x; 1.0968x over previous
//
#include <hip/hip_runtime.h>
#include <hip/hip_bf16.h>

typedef __attribute__((ext_vector_type(8))) short bfrag;
typedef __attribute__((ext_vector_type(4))) float f32x4;

// fast shifted softplus: __logf/__expf intrinsics (rel err ~2^-21, threshold 2.3e-2)
__device__ __forceinline__ float ssp_f(float x) {
    return fmaxf(x, 0.f) + __logf(1.f + __expf(-fabsf(x))) - 0.6931471805599453f;
}

__device__ __forceinline__ unsigned short f2b(float x) {
    __hip_bfloat16 h = __float2bfloat16(x);
    return *(unsigned short*)&h;
}

// ---------------- float dtype sniffer ----------------------------------------
__global__ void sniff_kernel(const unsigned int* __restrict__ raw, int* __restrict__ flag)
{
    __shared__ int cnt[256];
    const int t = threadIdx.x;
    unsigned int w = raw[t];
    unsigned int e = (w >> 7) & 0xFFu;
    cnt[t] = (e >= 100u && e <= 135u) ? 1 : 0;
    __syncthreads();
    for (int s = 128; s > 0; s >>= 1) {
        if (t < s) cnt[t] += cnt[t + s];
        __syncthreads();
    }
    if (t == 0) *flag = (cnt[0] >= 160) ? 1 : 0;   // 1 = floats are bf16
}

// ---------------- int width sniffer -------------------------------------------
__global__ void sniff_int_kernel(const unsigned int* __restrict__ z, int* __restrict__ iflag)
{
    __shared__ int cnt[128];
    const int t = threadIdx.x;
    cnt[t] = (z[2 * t + 1] == 0u) ? 1 : 0;
    __syncthreads();
    for (int s = 64; s > 0; s >>= 1) {
        if (t < s) cnt[t] += cnt[t + s];
        __syncthreads();
    }
    if (t == 0) *iflag = (cnt[0] >= 126) ? 1 : 0;  // 1 = ints are int64
}

// ---------------- fused convert of all 16 float tensors -----------------------
struct Cvt16 {
    const void* src[16];
    long off[17];
};

__global__ __launch_bounds__(256) void convert_fused_kernel(
    Cvt16 args, float* __restrict__ F, long total, const int* __restrict__ flag)
{
    long i = (long)blockIdx.x * 256 + threadIdx.x;
    if (i >= total) return;
    int lo = 0, hi = 16;
    while (hi - lo > 1) {
        int mid = (lo + hi) >> 1;
        if (i >= args.off[mid]) lo = mid; else hi = mid;
    }
    long loc = i - args.off[lo];
    if (*flag) F[i] = __bfloat162float(((const __hip_bfloat16*)args.src[lo])[loc]);
    else       F[i] = ((const float*)args.src[lo])[loc];
}

__global__ __launch_bounds__(256) void convert_int_kernel(
    const void* __restrict__ src, int* __restrict__ dst, int n,
    const int* __restrict__ iflag)
{
    int i = blockIdx.x * 256 + threadIdx.x;
    if (i >= n) return;
    if (*iflag) dst[i] = (int)(((const long long*)src)[i]);
    else        dst[i] = ((const int*)src)[i];
}

// ---------------- node embedding gather ---------------------------------------
__global__ __launch_bounds__(256) void embed_kernel(
    const int* __restrict__ z, const float* __restrict__ embf,
    float* __restrict__ h, int NH)
{
    int idx = blockIdx.x * 256 + threadIdx.x;
    if (idx >= NH) return;
    h[idx] = embf[z[idx >> 7] * 128 + (idx & 127)];
}

// ---------------- CSR build ----------------------------------------------------
__global__ __launch_bounds__(256) void zero_int_kernel(int* p, int n)
{
    int i = blockIdx.x * 256 + threadIdx.x;
    if (i < n) p[i] = 0;
}

__global__ __launch_bounds__(256) void hist_kernel(const int* __restrict__ col,
                                                   int* __restrict__ count, int E)
{
    int e = blockIdx.x * 256 + threadIdx.x;
    if (e < E) atomicAdd(&count[col[e]], 1);
}

__global__ __launch_bounds__(256) void scan_kernel(const int* __restrict__ count,
                                                   int* __restrict__ rowptr,
                                                   int* __restrict__ next, int N)
{
    __shared__ int part[256];
    const int t = threadIdx.x;
    const int chunk = (N + 255) / 256;
    const int lo = t * chunk, hi = min(lo + chunk, N);
    int s = 0;
    for (int i = lo; i < hi; ++i) s += count[i];
    part[t] = s;
    __syncthreads();
    if (t == 0) {
        int run = 0;
        for (int i = 0; i < 256; ++i) { int v = part[i]; part[i] = run; run += v; }
        rowptr[N] = run;
    }
    __syncthreads();
    int run = part[t];
    for (int i = lo; i < hi; ++i) {
        rowptr[i] = run; next[i] = run;
        run += count[i];
    }
}

__global__ __launch_bounds__(256) void slot_kernel(const int* __restrict__ col,
                                                   int* __restrict__ next,
                                                   int* __restrict__ slot, int E)
{
    int e = blockIdx.x * 256 + threadIdx.x;
    if (e < E) slot[e] = atomicAdd(&next[col[e]], 1);
}

__global__ __launch_bounds__(256) void perm_kernel(const int* __restrict__ slot,
                                                   int* __restrict__ perm, int E)
{
    int e = blockIdx.x * 256 + threadIdx.x;
    if (e < E) perm[slot[e]] = e;
}

// ---------------- pre-permute edge data into sorted order ---------------------
__global__ __launch_bounds__(256) void prep_edges_kernel(
    const float* __restrict__ posf, const int* __restrict__ row,
    const int* __restrict__ col, const float* __restrict__ eattrf,
    const int* __restrict__ perm,
    int* __restrict__ rowS, int* __restrict__ colS,
    float* __restrict__ CS, float* __restrict__ ewS,
    unsigned short* __restrict__ eaS, int E, int NB)
{
    int p = blockIdx.x * 256 + threadIdx.x;
    if (p >= E) return;
    const int e = perm[p];
    const int r = row[e], c = col[e];
    float dx = posf[r*3+0] - posf[c*3+0];
    float dy = posf[r*3+1] - posf[c*3+1];
    float dz = posf[r*3+2] - posf[c*3+2];
    float ew = sqrtf(dx*dx + dy*dy + dz*dz);
    rowS[p] = r; colS[p] = c; ewS[p] = ew;
    CS[p] = 0.5f * (cosf(ew * 0.3141592653589793f) + 1.0f);
    unsigned short* o = eaS + (long)p * 4;
    for (int q = 0; q < 4; ++q)
        o[q] = (q < NB) ? f2b(eattrf[(long)e * NB + q]) : (unsigned short)0;
}

// ---------------- weight transpose to bf16 N-major ----------------------------
__global__ __launch_bounds__(256) void wtrans_kernel(
    const float* __restrict__ src, unsigned short* __restrict__ dst,
    int K, int Kpad, int N)
{
    int idx = blockIdx.x * 256 + threadIdx.x;
    if (idx >= N * Kpad) return;
    int n = idx / Kpad, k = idx - n * Kpad;
    dst[idx] = (k < K) ? f2b(src[k * N + n]) : (unsigned short)0;
}

// node weights (cf1, cf2, lin): 3L matrices of 128x128, n-major bf16.
// dst matrix m = l*3 + fam at offset m*16384.
__global__ __launch_bounds__(256) void wtrans_node_kernel(
    const float* __restrict__ cf1, const float* __restrict__ cf2,
    const float* __restrict__ lin, unsigned short* __restrict__ dst, int total)
{
    int idx = blockIdx.x * 256 + threadIdx.x;
    if (idx >= total) return;
    int m = idx >> 14;
    int fam = m % 3, l = m / 3;
    int local = idx & 16383;
    int n = local >> 7, k = local & 127;
    const float* src = (fam == 0 ? cf1 : fam == 1 ? cf2 : lin) + (long)l * 16384;
    dst[idx] = f2b(src[k * 128 + n]);
}

// ---------------- fp32 node GEMM (fallback path only) -------------------------
template<int MODE>
__global__ __launch_bounds__(256) void node_gemm_tiled(
    const float* __restrict__ in, const float* __restrict__ W,
    const float* __restrict__ bias, float* __restrict__ out, int N)
{
    __shared__ float in_s[32][128];
    const int t = threadIdx.x;
    const long n0 = (long)blockIdx.x * 32;
    for (int i = t; i < 32 * 128; i += 256) {
        long n = n0 + (i >> 7);
        in_s[i >> 7][i & 127] = (n < N) ? in[n * 128 + (i & 127)] : 0.f;
    }
    __syncthreads();
    const int j = t & 31, sub = t >> 5;
    const int c4 = j * 4, rb = sub * 4;
    float acc[4][4];
    float4 bv = make_float4(0.f, 0.f, 0.f, 0.f);
    if (MODE != 0) bv = *(const float4*)(bias + c4);
    #pragma unroll
    for (int i = 0; i < 4; ++i) { acc[i][0]=bv.x; acc[i][1]=bv.y; acc[i][2]=bv.z; acc[i][3]=bv.w; }
    #pragma unroll 4
    for (int k = 0; k < 128; ++k) {
        const float4 wv = *(const float4*)(W + k * 128 + c4);
        #pragma unroll
        for (int i = 0; i < 4; ++i) {
            const float a = in_s[rb + i][k];
            acc[i][0] += a * wv.x; acc[i][1] += a * wv.y;
            acc[i][2] += a * wv.z; acc[i][3] += a * wv.w;
        }
    }
    #pragma unroll
    for (int i = 0; i < 4; ++i) {
        long n = n0 + rb + i;
        if (n >= N) continue;
        float4 o;
        if (MODE == 1) {
            o.x = ssp_f(acc[i][0]); o.y = ssp_f(acc[i][1]);
            o.z = ssp_f(acc[i][2]); o.w = ssp_f(acc[i][3]);
        } else {
            o.x = acc[i][0]; o.y = acc[i][1]; o.z = acc[i][2]; o.w = acc[i][3];
        }
        if (MODE == 2) {
            float4 p = *(const float4*)(out + n * 128 + c4);
            o.x += p.x; o.y += p.y; o.z += p.z; o.w += p.w;
        }
        *(float4*)(out + n * 128 + c4) = o;
    }
}

// ---------------- MFMA node GEMM: xh = h @ cf1 (no bias) ----------------------
__global__ __launch_bounds__(256) void node_gemm1_mfma(
    const float* __restrict__ in, const unsigned short* __restrict__ wt,
    float* __restrict__ out, int N)
{
    __shared__ __align__(16) short a_b[32][136];
    const int t = threadIdx.x;
    const long r0 = (long)blockIdx.x * 32;
    for (int i = t; i < 32 * 128; i += 256) {
        const int r = i >> 7, c = i & 127;
        long n = r0 + r;
        a_b[r][c] = (short)f2b((n < N) ? in[n * 128 + c] : 0.f);
    }
    __syncthreads();
    const int lane = t & 63, w = t >> 6;
    const int colL = lane & 15, quad = lane >> 4;
    const int m0 = (w & 1) * 16;
    f32x4 acc[4];
    #pragma unroll
    for (int tt = 0; tt < 4; ++tt) acc[tt] = (f32x4){0.f, 0.f, 0.f, 0.f};
    #pragma unroll
    for (int ks = 0; ks < 4; ++ks) {
        const bfrag a = *(const bfrag*)&a_b[m0 + colL][ks * 32 + quad * 8];
        #pragma unroll
        for (int tt = 0; tt < 4; ++tt) {
            const int n0 = ((w >> 1) * 4 + tt) * 16;
            const bfrag b = *(const bfrag*)&wt[(long)(n0 + colL) * 128 + ks * 32 + quad * 8];
            acc[tt] = __builtin_amdgcn_mfma_f32_16x16x32_bf16(a, b, acc[tt], 0, 0, 0);
        }
    }
    #pragma unroll
    for (int tt = 0; tt < 4; ++tt) {
        const int n0 = ((w >> 1) * 4 + tt) * 16;
        #pragma unroll
        for (int reg = 0; reg < 4; ++reg) {
            long n = r0 + m0 + quad * 4 + reg;
            if (n < N) out[n * 128 + n0 + colL] = acc[tt][reg];
        }
    }
}

// ------- MFMA fused node block: h += lin(ssp(agg @ cf2 + b2)) + blin ---------
__global__ __launch_bounds__(256) void node_gemm23_mfma(
    const float* __restrict__ in,
    const unsigned short* __restrict__ w1t, const float* __restrict__ b1,
    const unsigned short* __restrict__ w2t, const float* __restrict__ b2,
    float* __restrict__ h, int N)
{
    __shared__ __align__(16) short a_b[32][136];
    __shared__ __align__(16) short t_b[32][136];
    const int t = threadIdx.x;
    const long r0 = (long)blockIdx.x * 32;
    for (int i = t; i < 32 * 128; i += 256) {
        const int r = i >> 7, c = i & 127;
        long n = r0 + r;
        a_b[r][c] = (short)f2b((n < N) ? in[n * 128 + c] : 0.f);
    }
    __syncthreads();
    const int lane = t & 63, w = t >> 6;
    const int colL = lane & 15, quad = lane >> 4;
    const int m0 = (w & 1) * 16;
    {
        f32x4 acc[4];
        #pragma unroll
        for (int tt = 0; tt < 4; ++tt) acc[tt] = (f32x4){0.f, 0.f, 0.f, 0.f};
        #pragma unroll
        for (int ks = 0; ks < 4; ++ks) {
            const bfrag a = *(const bfrag*)&a_b[m0 + colL][ks * 32 + quad * 8];
            #pragma unroll
            for (int tt = 0; tt < 4; ++tt) {
                const int n0 = ((w >> 1) * 4 + tt) * 16;
                const bfrag b = *(const bfrag*)&w1t[(long)(n0 + colL) * 128 + ks * 32 + quad * 8];
                acc[tt] = __builtin_amdgcn_mfma_f32_16x16x32_bf16(a, b, acc[tt], 0, 0, 0);
            }
        }
        #pragma unroll
        for (int tt = 0; tt < 4; ++tt) {
            const int n0 = ((w >> 1) * 4 + tt) * 16;
            const float bcol = b1[n0 + colL];
            #pragma unroll
            for (int reg = 0; reg < 4; ++reg)
                t_b[m0 + quad * 4 + reg][n0 + colL] = (short)f2b(ssp_f(acc[tt][reg] + bcol));
        }
    }
    __syncthreads();
    {
        f32x4 acc[4];
        #pragma unroll
        for (int tt = 0; tt < 4; ++tt) acc[tt] = (f32x4){0.f, 0.f, 0.f, 0.f};
        #pragma unroll
        for (int ks = 0; ks < 4; ++ks) {
            const bfrag a = *(const bfrag*)&t_b[m0 + colL][ks * 32 + quad * 8];
            #pragma unroll
            for (int tt = 0; tt < 4; ++tt) {
                const int n0 = ((w >> 1) * 4 + tt) * 16;
                const bfrag b = *(const bfrag*)&w2t[(long)(n0 + colL) * 128 + ks * 32 + quad * 8];
                acc[tt] = __builtin_amdgcn_mfma_f32_16x16x32_bf16(a, b, acc[tt], 0, 0, 0);
            }
        }
        #pragma unroll
        for (int tt = 0; tt < 4; ++tt) {
            const int n0 = ((w >> 1) * 4 + tt) * 16;
            const int cg = n0 + colL;
            const float bcol = b2[cg];
            #pragma unroll
            for (int reg = 0; reg < 4; ++reg) {
                long n = r0 + m0 + quad * 4 + reg;
                if (n < N) h[n * 128 + cg] += acc[tt][reg] + bcol;
            }
        }
    }
}

// ---------------- MFMA edge kernel — r16-measured config (287 us) -------------
__global__ __launch_bounds__(256) void edge_mfma(
    const int* __restrict__ rowS, const int* __restrict__ colS,
    const float* __restrict__ CS, const float* __restrict__ ewS,
    const unsigned short* __restrict__ eaS,
    const unsigned short* __restrict__ w1t, const float* __restrict__ b1,
    const unsigned short* __restrict__ w2t, const float* __restrict__ b2,
    const float* __restrict__ xh, float* __restrict__ agg,
    int E, int NB, int F50, float delta, float coeff)
{
    __shared__ __align__(16) short ea_b[32][64];
    __shared__ __align__(16) short t_b[32][128];
    __shared__ float runbuf[32][136];
    __shared__ int   row_s[32];
    __shared__ int   col_s[32];
    __shared__ float C_s[32];
    __shared__ float ew_s[32];
    __shared__ int   runcol_s[32];
    __shared__ int   runstart_s[33];
    __shared__ int   nruns_s;

    const int t = threadIdx.x;
    const long p0 = (long)blockIdx.x * 32;

    if (t < 32) {
        long p = p0 + t; if (p >= E) p = E - 1;
        row_s[t] = rowS[p];
        col_s[t] = colS[p];
        C_s[t]   = (p0 + t < E) ? CS[p] : 0.f;
        ew_s[t]  = ewS[p];
        if (t == 0) {
            int nr = 0;
            for (int i = 0; i < 32; ++i) {
                if (i == 0 || col_s[i] != col_s[i - 1]) {
                    runcol_s[nr] = col_s[i];
                    runstart_s[nr] = i;
                    ++nr;
                }
            }
            runstart_s[nr] = 32;
            nruns_s = nr;
        }
    }
    __syncthreads();
    for (int i = t; i < 32 * 64; i += 256) {
        const int e = i >> 6, k = i & 63;
        long p = p0 + e; if (p >= E) p = E - 1;
        unsigned short v;
        if (k < NB)        v = eaS[p * 4 + k];
        else if (k < F50) {
            float d = ew_s[e] - (float)(k - NB) * delta;
            v = f2b(__expf(coeff * d * d));
        } else             v = 0;
        ea_b[e][k] = (short)v;
    }
    __syncthreads();

    const int lane = t & 63;
    const int w    = t >> 6;
    const int colL = lane & 15;
    const int quad = lane >> 4;
    const int m0   = (w & 1) * 16;

    {
        f32x4 acc[4];
        #pragma unroll
        for (int tt = 0; tt < 4; ++tt) acc[tt] = (f32x4){0.f, 0.f, 0.f, 0.f};
        #pragma unroll
        for (int ks = 0; ks < 2; ++ks) {
            const bfrag a = *(const bfrag*)&ea_b[m0 + colL][ks * 32 + quad * 8];
            #pragma unroll
            for (int tt = 0; tt < 4; ++tt) {
                const int n0 = ((w >> 1) * 4 + tt) * 16;
                const bfrag b = *(const bfrag*)&w1t[(long)(n0 + colL) * 64 + ks * 32 + quad * 8];
                acc[tt] = __builtin_amdgcn_mfma_f32_16x16x32_bf16(a, b, acc[tt], 0, 0, 0);
            }
        }
        #pragma unroll
        for (int tt = 0; tt < 4; ++tt) {
            const int n0 = ((w >> 1) * 4 + tt) * 16;
            const float bcol = b1[n0 + colL];
            #pragma unroll
            for (int reg = 0; reg < 4; ++reg) {
                float v = ssp_f(acc[tt][reg] + bcol);
                t_b[m0 + quad * 4 + reg][n0 + colL] = (short)f2b(v);
            }
        }
    }
    __syncthreads();

    {
        f32x4 acc[4];
        #pragma unroll
        for (int tt = 0; tt < 4; ++tt) acc[tt] = (f32x4){0.f, 0.f, 0.f, 0.f};
        #pragma unroll
        for (int ks = 0; ks < 4; ++ks) {
            const bfrag a = *(const bfrag*)&t_b[m0 + colL][ks * 32 + quad * 8];
            #pragma unroll
            for (int tt = 0; tt < 4; ++tt) {
                const int n0 = ((w >> 1) * 4 + tt) * 16;
                const bfrag b = *(const bfrag*)&w2t[(long)(n0 + colL) * 128 + ks * 32 + quad * 8];
                acc[tt] = __builtin_amdgcn_mfma_f32_16x16x32_bf16(a, b, acc[tt], 0, 0, 0);
            }
        }
        const int ebase = m0 + quad * 4;
        #pragma unroll
        for (int tt = 0; tt < 4; ++tt) {
            const int n0 = ((w >> 1) * 4 + tt) * 16;
            const int cg = n0 + colL;
            const float bcol = b2[cg];
            #pragma unroll
            for (int reg = 0; reg < 4; ++reg) {
                const int e = ebase + reg;
                const float v = acc[tt][reg] + bcol;
                runbuf[e][cg] = v * C_s[e] * xh[(long)row_s[e] * 128 + cg];
            }
        }
    }
    __syncthreads();

    const int nr = nruns_s;
    const int cc = t & 127;
    for (int r = t >> 7; r < nr; r += 2) {
        float a = 0.f;
        const int s1 = runstart_s[r + 1];
        for (int e = runstart_s[r]; e < s1; ++e)
            a += runbuf[e][cc];
        atomicAdd(&agg[(long)runcol_s[r] * 128 + cc], a);
    }
}

// ---------------- fp32 atomic edge kernel (fallback) --------------------------
__global__ __launch_bounds__(256) void edge_atomic(
    const float* __restrict__ posf,
    const int* __restrict__ row, const int* __restrict__ col,
    const float* __restrict__ eattrf,
    const float* __restrict__ w1, const float* __restrict__ b1,
    const float* __restrict__ w2, const float* __restrict__ b2,
    const float* __restrict__ xh, float* __restrict__ agg,
    int E, int NB, int F50, float delta, float coeff)
{
    __shared__ float ea_s[32][52];
    __shared__ float t_s[32][128];
    __shared__ int   row_s[32];
    __shared__ int   col_s[32];
    __shared__ float C_s[32];
    __shared__ float ew_s[32];

    const int t = threadIdx.x;
    const long e0 = (long)blockIdx.x * 32;

    if (t < 32) {
        long e = e0 + t; if (e >= E) e = E - 1;
        const int r = row[e], c = col[e];
        row_s[t] = r; col_s[t] = c;
        float dx = posf[r*3+0] - posf[c*3+0];
        float dy = posf[r*3+1] - posf[c*3+1];
        float dz = posf[r*3+2] - posf[c*3+2];
        float ew = sqrtf(dx*dx + dy*dy + dz*dz);
        ew_s[t] = ew;
        C_s[t]  = (e0 + t < E) ? 0.5f * (cosf(ew * 0.3141592653589793f) + 1.0f) : 0.f;
        for (int q = 0; q < NB; ++q)
            ea_s[t][q] = eattrf[e * NB + q];
    }
    __syncthreads();
    {
        const int NGS = F50 - NB;
        for (int i = t; i < 32 * NGS; i += 256) {
            const int e = i / NGS, g = i - e * NGS;
            const float d = ew_s[e] - (float)g * delta;
            ea_s[e][NB + g] = __expf(coeff * d * d);
        }
    }
    __syncthreads();

    const int j = t & 31, sub = t >> 5;
    const int c4 = j * 4, eb = sub * 4;
    float acc[4][4];
    {
        const float4 bv = *(const float4*)(b1 + c4);
        #pragma unroll
        for (int i = 0; i < 4; ++i) { acc[i][0]=bv.x; acc[i][1]=bv.y; acc[i][2]=bv.z; acc[i][3]=bv.w; }
        for (int k = 0; k < F50; ++k) {
            const float4 wv = *(const float4*)(w1 + k * 128 + c4);
            #pragma unroll
            for (int i = 0; i < 4; ++i) {
                const float a = ea_s[eb + i][k];
                acc[i][0] += a * wv.x; acc[i][1] += a * wv.y;
                acc[i][2] += a * wv.z; acc[i][3] += a * wv.w;
            }
        }
        #pragma unroll
        for (int i = 0; i < 4; ++i) {
            float4 o;
            o.x = ssp_f(acc[i][0]); o.y = ssp_f(acc[i][1]);
            o.z = ssp_f(acc[i][2]); o.w = ssp_f(acc[i][3]);
            *(float4*)&t_s[eb + i][c4] = o;
        }
    }
    __syncthreads();
    {
        const float4 bv = *(const float4*)(b2 + c4);
        #pragma unroll
        for (int i = 0; i < 4; ++i) { acc[i][0]=bv.x; acc[i][1]=bv.y; acc[i][2]=bv.z; acc[i][3]=bv.w; }
        #pragma unroll 4
        for (int k = 0; k < 128; ++k) {
            const float4 wv = *(const float4*)(w2 + k * 128 + c4);
            #pragma unroll
            for (int i = 0; i < 4; ++i) {
                const float a = t_s[eb + i][k];
                acc[i][0] += a * wv.x; acc[i][1] += a * wv.y;
                acc[i][2] += a * wv.z; acc[i][3] += a * wv.w;
            }
        }
    }
    #pragma unroll
    for (int i = 0; i < 4; ++i) {
        const int e = eb + i;
        if (e0 + e >= E) continue;
        const float Ce = C_s[e];
        const float4 xv = *(const float4*)(xh + (long)row_s[e] * 128 + c4);
        float* ag = agg + (long)col_s[e] * 128 + c4;
        atomicAdd(ag + 0, acc[i][0] * Ce * xv.x);
        atomicAdd(ag + 1, acc[i][1] * Ce * xv.y);
        atomicAdd(ag + 2, acc[i][2] * Ce * xv.z);
        atomicAdd(ag + 3, acc[i][3] * Ce * xv.w);
    }
}

// ---------------- readout ------------------------------------------------------
__global__ __launch_bounds__(128) void readout_simple(
    const float* __restrict__ h,
    const float* __restrict__ o1w, const float* __restrict__ o1b,
    const float* __restrict__ o2w, const float* __restrict__ o2b,
    const int* __restrict__ batch, float* __restrict__ accb)
{
    __shared__ float hr[128];
    __shared__ float vv[64];
    const int n = blockIdx.x;
    const int t = threadIdx.x;
    hr[t] = h[(long)n * 128 + t];
    __syncthreads();
    if (t < 64) {
        float a = o1b[t];
        #pragma unroll 8
        for (int k = 0; k < 128; ++k)
            a = fmaf(hr[k], o1w[k * 64 + t], a);
        vv[t] = ssp_f(a) * o2w[t];
    }
    __syncthreads();
    if (t < 32) vv[t] += vv[t + 32];
    __syncthreads();
    if (t < 16) vv[t] += vv[t + 16];
    __syncthreads();
    if (t < 8)  vv[t] += vv[t + 8];
    __syncthreads();
    if (t < 4)  vv[t] += vv[t + 4];
    __syncthreads();
    if (t < 2)  vv[t] += vv[t + 2];
    __syncthreads();
    if (t == 0) atomicAdd(&accb[batch[n]], vv[0] + vv[1] + o2b[0]);
}

// output is FLOAT32 (verified round 11)
__global__ void finalize_kernel(const float* __restrict__ accb,
                                float* __restrict__ out, int B)
{
    int t = blockIdx.x * 256 + threadIdx.x;
    if (t < B) out[t] = accb[t];
}

// ---------------- launch -------------------------------------------------------
extern "C" void kernel_launch(void* const* d_in, const int* in_sizes, int n_in,
                              void* d_out, int out_size, void* d_ws, size_t ws_size,
                              hipStream_t stream)
{
    const int N   = in_sizes[0];
    const int E   = in_sizes[3] / 2;
    const int B   = out_size;
    const int H   = 128;
    const int L   = in_sizes[7] / H;
    const int NB  = in_sizes[4] / E;
    const int F50 = in_sizes[6] / (L * H);
    const int NGS = F50 - NB;
    const float delta = 10.0f / (float)(NGS - 1);
    const float coeff = -0.5f / (delta * delta);

    const int fidx[16] = {1, 4, 5, 6, 7, 8, 9, 10, 11, 12, 13, 14, 15, 16, 17, 18};
    Cvt16 cv;
    cv.off[0] = 0;
    for (int i = 0; i < 16; ++i) {
        cv.src[i] = d_in[fidx[i]];
        cv.off[i + 1] = cv.off[i] + in_sizes[fidx[i]];
    }
    const long ftot = cv.off[16];

    float* F = (float*)d_ws;
    long base = (ftot + 3) & ~3L;
    float* h    = F + base;
    float* xh   = h + (long)N * H;
    float* agg  = xh + (long)N * H;
    float* accb = agg + (long)N * H;
    int*   flag  = (int*)(accb + ((B + 3) & ~3));
    int*   iflag = flag + 1;
    int*   zi     = flag + 4;
    int*   batchi = zi + N;
    int*   eidxi  = batchi + N;
    int*   count  = eidxi + 2 * E;
    int*   rowptr = count + N;
    int*   next   = rowptr + N + 1;
    int*   slot   = next + N;
    int*   perm   = slot + E;
    int*   rowS   = perm + E;
    int*   colS   = rowS + E;
    float* CS     = (float*)(colS + E);
    float* ewS    = CS + E;
    unsigned short* eaS = (unsigned short*)(ewS + E);      // 4E ushorts
    unsigned short* w1t = eaS + 4L * E;                    // L*128*64
    unsigned short* w2t = w1t + (long)L * 128 * 64;        // L*128*128
    unsigned short* nwt = w2t + (long)L * 128 * 128;       // 3L*128*128
    long used_bytes = (long)((char*)(nwt + 3L * L * 128 * 128) - (char*)d_ws);
    const bool use_fast = (used_bytes <= (long)ws_size) && (F50 <= 64) && (NB <= 4);

    sniff_kernel<<<1, 256, 0, stream>>>((const unsigned int*)d_in[5], flag);
    sniff_int_kernel<<<1, 128, 0, stream>>>((const unsigned int*)d_in[0], iflag);

    convert_fused_kernel<<<(int)((ftot + 255) / 256), 256, 0, stream>>>(cv, F, ftot, flag);
    convert_int_kernel<<<(N + 255) / 256, 256, 0, stream>>>(d_in[0], zi, N, iflag);
    convert_int_kernel<<<(N + 255) / 256, 256, 0, stream>>>(d_in[2], batchi, N, iflag);
    convert_int_kernel<<<(2 * E + 255) / 256, 256, 0, stream>>>(d_in[3], eidxi, 2 * E, iflag);

    const float* posf   = F + cv.off[0];
    const float* eattrf = F + cv.off[1];
    const float* embf   = F + cv.off[2];
    const float* w1   = F + cv.off[3];  const float* b1   = F + cv.off[4];
    const float* w2   = F + cv.off[5];  const float* b2   = F + cv.off[6];
    const float* cf1  = F + cv.off[7];  const float* cf2  = F + cv.off[8];
    const float* cf2b = F + cv.off[9];  const float* lin  = F + cv.off[10];
    const float* linb = F + cv.off[11]; const float* o1   = F + cv.off[12];
    const float* o1b  = F + cv.off[13]; const float* o2   = F + cv.off[14];
    const float* o2b  = F + cv.off[15];

    if (use_fast) {
        zero_int_kernel<<<(N + 255) / 256, 256, 0, stream>>>(count, N);
        hist_kernel<<<(E + 255) / 256, 256, 0, stream>>>(eidxi + E, count, E);
        scan_kernel<<<1, 256, 0, stream>>>(count, rowptr, next, N);
        slot_kernel<<<(E + 255) / 256, 256, 0, stream>>>(eidxi + E, next, slot, E);
        perm_kernel<<<(E + 255) / 256, 256, 0, stream>>>(slot, perm, E);
        prep_edges_kernel<<<(E + 255) / 256, 256, 0, stream>>>(
            posf, eidxi, eidxi + E, eattrf, perm, rowS, colS, CS, ewS, eaS, E, NB);
        for (int l = 0; l < L; ++l) {
            wtrans_kernel<<<(128 * 64 + 255) / 256, 256, 0, stream>>>(
                w1 + (long)l * F50 * H, w1t + (long)l * 128 * 64, F50, 64, 128);
            wtrans_kernel<<<(128 * 128 + 255) / 256, 256, 0, stream>>>(
                w2 + (long)l * H * H, w2t + (long)l * 128 * 128, 128, 128, 128);
        }
        const int ntot = 3 * L * 128 * 128;
        wtrans_node_kernel<<<(ntot + 255) / 256, 256, 0, stream>>>(cf1, cf2, lin, nwt, ntot);
    }

    embed_kernel<<<(N * H + 255) / 256, 256, 0, stream>>>(zi, embf, h, N * H);
    hipMemsetAsync(accb, 0, (size_t)B * sizeof(float), stream);

    const int ngemm = (N + 31) / 32;
    const int nedge = (E + 31) / 32;
    for (int l = 0; l < L; ++l) {
        hipMemsetAsync(agg, 0, (size_t)N * H * sizeof(float), stream);
        if (use_fast) {
            node_gemm1_mfma<<<ngemm, 256, 0, stream>>>(
                h, nwt + (long)(l * 3 + 0) * 16384, xh, N);
            edge_mfma<<<nedge, 256, 0, stream>>>(
                rowS, colS, CS, ewS, eaS,
                w1t + (long)l * 128 * 64, b1 + (long)l * H,
                w2t + (long)l * 128 * 128, b2 + (long)l * H,
                xh, agg, E, NB, F50, delta, coeff);
            node_gemm23_mfma<<<ngemm, 256, 0, stream>>>(
                agg, nwt + (long)(l * 3 + 1) * 16384, cf2b + (long)l * H,
                nwt + (long)(l * 3 + 2) * 16384, linb + (long)l * H, h, N);
        } else {
            node_gemm_tiled<0><<<ngemm, 256, 0, stream>>>(h, cf1 + (long)l * H * H, nullptr, xh, N);
            edge_atomic<<<nedge, 256, 0, stream>>>(
                posf, eidxi, eidxi + E, eattrf,
                w1 + (long)l * F50 * H, b1 + (long)l * H,
                w2 + (long)l * H * H,  b2 + (long)l * H,
                xh, agg, E, NB, F50, delta, coeff);
            node_gemm_tiled<1><<<ngemm, 256, 0, stream>>>(agg, cf2 + (long)l * H * H, cf2b + (long)l * H, xh, N);
            node_gemm_tiled<2><<<ngemm, 256, 0, stream>>>(xh, lin + (long)l * H * H, linb + (long)l * H, h, N);
        }
    }

    readout_simple<<<N, 128, 0, stream>>>(h, o1, o1b, o2, o2b, batchi, accb);
    finalize_kernel<<<(B + 255) / 256, 256, 0, stream>>>(accb, (float*)d_out, B);
}